// Round 1
// baseline (332.760 us; speedup 1.0000x reference)
//
#include <hip/hip_runtime.h>

// tanh(x) = (e^{2x}-1)/(e^{2x}+1) = 1 - 2/(2^{c x}+1), c = 2*log2(e).
// Wnet/bnet are pre-scaled by c (prep kernel) so the pre-activation IS c*x.
#define C_SCALE 2.8853900817779268f
#define LOG2E   1.4426950408889634f

#if __has_builtin(__builtin_amdgcn_exp2f)
#define EXP2F(x) __builtin_amdgcn_exp2f(x)
#else
extern "C" __device__ float __ocml_native_exp2_f32(float);
#define EXP2F(x) __ocml_native_exp2_f32(x)
#endif

__device__ __forceinline__ float tanh_scaled(float p) {
    // p = 2*log2(e)*x
    float t = EXP2F(p);
    float r = __builtin_amdgcn_rcpf(t + 1.0f);
    return __builtin_fmaf(-2.0f, r, 1.0f);
}

// Pre-scale Wnet (48) + bnet (4) by C_SCALE into ws[0..51].
__global__ void trm_prep(const float* __restrict__ Wnet,
                         const float* __restrict__ bnet,
                         float* __restrict__ ws) {
    int i = threadIdx.x;
    if (i < 48) ws[i] = Wnet[i] * C_SCALE;
    if (i < 4)  ws[48 + i] = bnet[i] * C_SCALE;
}

__global__ void __launch_bounds__(256) trm_main(
    const float* __restrict__ xs,    // [B,2]
    const float* __restrict__ Wx,    // [2,4]
    const float* __restrict__ bx,    // [4]
    const float* __restrict__ by,    // [4]
    const float* __restrict__ Wdec,  // [4,1]
    const float* __restrict__ bdec,  // [1]
    const float* __restrict__ Wq,    // [4,1]
    const float* __restrict__ bq,    // [1]
    const int*   __restrict__ Tp,    // scalar
    const int*   __restrict__ np,    // scalar
    const float* __restrict__ wsc,   // 48 scaled Wnet + 4 scaled bnet
    float* __restrict__ out,         // [2*B] : y_hat then q_hat
    int B)
{
    int i = blockIdx.x * blockDim.x + threadIdx.x;
    if (i >= B) return;

    const int T = *Tp;
    const int n = *np;

    float2 x = reinterpret_cast<const float2*>(xs)[i];

    float xe[4], ye[4], z[4], cx[4], cy[4], cyy[4];
    #pragma unroll
    for (int j = 0; j < 4; ++j) {
        xe[j] = __builtin_fmaf(x.y, Wx[4 + j], __builtin_fmaf(x.x, Wx[j], bx[j]));
        ye[j] = by[j];   // ys = 0 -> ys_e = by ; Wy unused
        z[j]  = 0.0f;
    }
    // cx[j] = bnet'[j] + sum_k xe[k]*Wnet'[k][j]  (loop-invariant over ALL steps)
    #pragma unroll
    for (int j = 0; j < 4; ++j) {
        float a = wsc[48 + j];
        #pragma unroll
        for (int k = 0; k < 4; ++k) a = __builtin_fmaf(xe[k], wsc[k * 4 + j], a);
        cx[j] = a;
    }

    for (int t = 0; t < T; ++t) {
        // cy[j] = cx[j] + sum_k ye[k]*Wnet'[4+k][j]   (invariant over the n z-steps)
        // cyy[j] = bnet' + ye-part = cy - cx + bnet'   (y-step has zero x input)
        #pragma unroll
        for (int j = 0; j < 4; ++j) {
            float a = cx[j];
            #pragma unroll
            for (int k = 0; k < 4; ++k) a = __builtin_fmaf(ye[k], wsc[(4 + k) * 4 + j], a);
            cy[j]  = a;
            cyy[j] = (a - cx[j]) + wsc[48 + j];
        }
        for (int s = 0; s < n; ++s) {
            float p[4];
            #pragma unroll
            for (int j = 0; j < 4; ++j) {
                float a = cy[j];
                #pragma unroll
                for (int k = 0; k < 4; ++k) a = __builtin_fmaf(z[k], wsc[(8 + k) * 4 + j], a);
                p[j] = a;
            }
            #pragma unroll
            for (int j = 0; j < 4; ++j) z[j] = tanh_scaled(p[j]);
        }
        {   // y-step: ys_e = tanh(concat(0, ys_e, zs) @ Wnet + bnet)
            float p[4];
            #pragma unroll
            for (int j = 0; j < 4; ++j) {
                float a = cyy[j];
                #pragma unroll
                for (int k = 0; k < 4; ++k) a = __builtin_fmaf(z[k], wsc[(8 + k) * 4 + j], a);
                p[j] = a;
            }
            #pragma unroll
            for (int j = 0; j < 4; ++j) ye[j] = tanh_scaled(p[j]);
        }
    }

    float yh = bdec[0];
    float qh = bq[0];
    #pragma unroll
    for (int k = 0; k < 4; ++k) {
        yh = __builtin_fmaf(ye[k], Wdec[k], yh);
        qh = __builtin_fmaf(ye[k], Wq[k], qh);
    }
    // sigmoid(q) = 1/(1 + 2^{-q*log2e})
    float e = EXP2F(-qh * LOG2E);
    float q = __builtin_amdgcn_rcpf(1.0f + e);

    out[i]     = yh;
    out[B + i] = q;
}

extern "C" void kernel_launch(void* const* d_in, const int* in_sizes, int n_in,
                              void* d_out, int out_size, void* d_ws, size_t ws_size,
                              hipStream_t stream) {
    const float* xs   = (const float*)d_in[0];
    const float* Wx   = (const float*)d_in[1];
    const float* bx   = (const float*)d_in[2];
    // d_in[3] = Wy (unused: ys starts at zero)
    const float* by   = (const float*)d_in[4];
    const float* Wnet = (const float*)d_in[5];
    const float* bnet = (const float*)d_in[6];
    const float* Wdec = (const float*)d_in[7];
    const float* bdec = (const float*)d_in[8];
    const float* Wq   = (const float*)d_in[9];
    const float* bq   = (const float*)d_in[10];
    const int*   Tp   = (const int*)d_in[11];
    const int*   np   = (const int*)d_in[12];

    float* ws  = (float*)d_ws;
    float* out = (float*)d_out;
    int B = in_sizes[0] / 2;

    trm_prep<<<1, 64, 0, stream>>>(Wnet, bnet, ws);
    trm_main<<<(B + 255) / 256, 256, 0, stream>>>(
        xs, Wx, bx, by, Wdec, bdec, Wq, bq, Tp, np, ws, out, B);
}